// Round 1
// baseline (2878.731 us; speedup 1.0000x reference)
//
#include <hip/hip_runtime.h>

// GCN: x1 = relu(Agg(x@W1)+b1); x2 = relu(Agg(x1@W2)+b2); out = [x1,x2]@linW + linb
// Agg(h)[i] = dinv[i]^2*h[i] + sum_{e: dst=i} dinv[src]*dinv[i]*h[src]
// n = 50000 (divisible by 16), D = 128, E = 800000.

#define D128 128

__global__ void k_init_deg(int* __restrict__ degc, int n) {
    int i = blockIdx.x * 256 + threadIdx.x;
    if (i < n) degc[i] = 1;  // self loop
}

__global__ void k_count(const int* __restrict__ dst, int* __restrict__ degc, int E) {
    int e = blockIdx.x * 256 + threadIdx.x;
    if (e < E) atomicAdd(&degc[dst[e]], 1);
}

__global__ void k_dinv(const int* __restrict__ degc, float* __restrict__ dinv, int n) {
    int i = blockIdx.x * 256 + threadIdx.x;
    if (i < n) dinv[i] = rsqrtf((float)degc[i]);
}

// C[row0..row0+16)[0..128) = A[rows]@W (K=128), optional bias, optional accumulate.
// Requires n % 16 == 0 (50000 = 16*3125).
__global__ __launch_bounds__(256) void k_gemm128(
    const float* __restrict__ A, const float* __restrict__ W,
    const float* __restrict__ bias, float* __restrict__ C, int accumulate)
{
    __shared__ float Ws[128 * 128];   // 64 KB
    __shared__ float As[16 * 128];    // 8 KB
    int tid = threadIdx.x;

    const float4* W4 = (const float4*)W;
    float4* Ws4 = (float4*)Ws;
#pragma unroll
    for (int it = 0; it < 16; ++it)
        Ws4[it * 256 + tid] = W4[it * 256 + tid];

    long long row0 = (long long)blockIdx.x * 16;
    const float4* A4 = (const float4*)(A + row0 * D128);
    float4* As4 = (float4*)As;
    As4[tid] = A4[tid];
    As4[256 + tid] = A4[256 + tid];
    __syncthreads();

    int cp = tid & 63;   // column pair 0..63 -> cols 2cp, 2cp+1
    int rq = tid >> 6;   // row quad 0..3 -> rows rq*4..rq*4+3
    float2 acc[4] = {{0.f,0.f},{0.f,0.f},{0.f,0.f},{0.f,0.f}};

#pragma unroll 8
    for (int k = 0; k < 128; ++k) {
        float2 w = *(const float2*)&Ws[k * 128 + cp * 2];
#pragma unroll
        for (int r = 0; r < 4; ++r) {
            float a = As[(rq * 4 + r) * 128 + k];  // wave-broadcast
            acc[r].x += a * w.x;
            acc[r].y += a * w.y;
        }
    }

    float2 bv = {0.f, 0.f};
    if (bias) bv = *(const float2*)&bias[cp * 2];
#pragma unroll
    for (int r = 0; r < 4; ++r) {
        long long row = row0 + rq * 4 + r;
        float2* Cp = (float2*)&C[row * D128 + cp * 2];
        float2 v = acc[r];
        v.x += bv.x; v.y += bv.y;
        if (accumulate) { float2 old = *Cp; v.x += old.x; v.y += old.y; }
        *Cp = v;
    }
}

// agg[i] = dinv[i]^2 * h[i]  (self-loop term), float4 over n*32 elements
__global__ void k_agg_init(const float* __restrict__ h, const float* __restrict__ dinv,
                           float* __restrict__ agg, int n) {
    int idx = blockIdx.x * 256 + threadIdx.x;
    if (idx >= n * 32) return;
    int i = idx >> 5;
    float dv = dinv[i];
    float s = dv * dv;
    float4 hv = ((const float4*)h)[idx];
    float4 o = {s * hv.x, s * hv.y, s * hv.z, s * hv.w};
    ((float4*)agg)[idx] = o;
}

// agg[dst] += dinv[src]*dinv[dst]*h[src] ; one thread per (edge, 4-channel chunk)
__global__ __launch_bounds__(256) void k_agg_edges(
    const int* __restrict__ src, const int* __restrict__ dst,
    const float* __restrict__ dinv, const float* __restrict__ h,
    float* __restrict__ agg, int E)
{
    int gid = blockIdx.x * 256 + threadIdx.x;
    int e = gid >> 5;
    if (e >= E) return;
    int q = gid & 31;
    int s = src[e], d = dst[e];
    float norm = dinv[s] * dinv[d];
    float4 hv = ((const float4*)(h + (size_t)s * D128))[q];
    float* ap = agg + (size_t)d * D128 + q * 4;
    unsafeAtomicAdd(ap + 0, norm * hv.x);
    unsafeAtomicAdd(ap + 1, norm * hv.y);
    unsafeAtomicAdd(ap + 2, norm * hv.z);
    unsafeAtomicAdd(ap + 3, norm * hv.w);
}

// o = relu(agg + b)
__global__ void k_bias_relu(const float* __restrict__ agg, const float* __restrict__ b,
                            float* __restrict__ o, int n) {
    int idx = blockIdx.x * 256 + threadIdx.x;
    if (idx >= n * 32) return;
    int q = idx & 31;
    float4 a = ((const float4*)agg)[idx];
    float4 bv = ((const float4*)b)[q];
    float4 v = {fmaxf(a.x + bv.x, 0.f), fmaxf(a.y + bv.y, 0.f),
                fmaxf(a.z + bv.z, 0.f), fmaxf(a.w + bv.w, 0.f)};
    ((float4*)o)[idx] = v;
}

extern "C" void kernel_launch(void* const* d_in, const int* in_sizes, int n_in,
                              void* d_out, int out_size, void* d_ws, size_t ws_size,
                              hipStream_t stream) {
    const float* x    = (const float*)d_in[0];
    const int*   ei   = (const int*)d_in[1];
    const float* W1   = (const float*)d_in[2];
    const float* b1   = (const float*)d_in[3];
    const float* W2   = (const float*)d_in[4];
    const float* b2   = (const float*)d_in[5];
    const float* linW = (const float*)d_in[6];
    const float* linb = (const float*)d_in[7];

    int n = in_sizes[0] / D128;
    int E = in_sizes[1] / 2;
    const int* src = ei;
    const int* dst = ei + E;

    float* out = (float*)d_out;
    float* ws  = (float*)d_ws;

    // workspace layout (floats): degc[n] | dinv[n] | agg[n*128] | x1[n*128] | x2[n*128]
    int*   degc = (int*)ws;
    float* dinv = ws + n;
    float* agg  = ws + 2 * (size_t)n;
    float* x1   = agg + (size_t)n * D128;
    float* x2   = x1 + (size_t)n * D128;
    float* h    = out;  // reuse output buffer as GEMM scratch for h1/h2

    int gn = (n + 255) / 256;
    int gE = (E + 255) / 256;
    int gemmBlocks = n / 16;               // n % 16 == 0
    int gv = (n * 32 + 255) / 256;         // float4 elementwise over n*128
    int ge = ((E * 32) + 255) / 256;       // per (edge, chunk-of-4)

    // degrees + normalization
    k_init_deg<<<gn, 256, 0, stream>>>(degc, n);
    k_count<<<gE, 256, 0, stream>>>(dst, degc, E);
    k_dinv<<<gn, 256, 0, stream>>>(degc, dinv, n);

    // layer 1
    k_gemm128<<<gemmBlocks, 256, 0, stream>>>(x, W1, nullptr, h, 0);
    k_agg_init<<<gv, 256, 0, stream>>>(h, dinv, agg, n);
    k_agg_edges<<<ge, 256, 0, stream>>>(src, dst, dinv, h, agg, E);
    k_bias_relu<<<gv, 256, 0, stream>>>(agg, b1, x1, n);

    // layer 2
    k_gemm128<<<gemmBlocks, 256, 0, stream>>>(x1, W2, nullptr, h, 0);
    k_agg_init<<<gv, 256, 0, stream>>>(h, dinv, agg, n);
    k_agg_edges<<<ge, 256, 0, stream>>>(src, dst, dinv, h, agg, E);
    k_bias_relu<<<gv, 256, 0, stream>>>(agg, b2, x2, n);

    // final: out = x1 @ linW[0:128] + x2 @ linW[128:256] + linb
    k_gemm128<<<gemmBlocks, 256, 0, stream>>>(x1, linW, nullptr, out, 0);
    k_gemm128<<<gemmBlocks, 256, 0, stream>>>(x2, linW + 128 * 128, linb, out, 1);
}

// Round 2
// 451.324 us; speedup vs baseline: 6.3784x; 6.3784x over previous
//
#include <hip/hip_runtime.h>

// GCN: x1 = relu(Agg(x@W1)+b1); x2 = relu(Agg(x1@W2)+b2); out = [x1,x2]@linW + linb
// Agg(h)[i] = dinv[i]^2*h[i] + sum_{e: dst=i} dinv[src]*dinv[i]*h[src]
// Strategy: counting-sort edges by dst into CSR, then per-node register reduction
// (no fp32 atomics). n = 50000, D = 128, E = 800000.

#define D128 128

// ---------- degree / normalization ----------
__global__ void k_zero_int(int* __restrict__ p, int n) {
    int i = blockIdx.x * 256 + threadIdx.x;
    if (i < n) p[i] = 0;
}

__global__ void k_count(const int* __restrict__ dst, int* __restrict__ indeg, int E) {
    int e = blockIdx.x * 256 + threadIdx.x;
    if (e < E) atomicAdd(&indeg[dst[e]], 1);
}

__global__ void k_dinv(const int* __restrict__ indeg, float* __restrict__ dinv, int n) {
    int i = blockIdx.x * 256 + threadIdx.x;
    if (i < n) dinv[i] = rsqrtf((float)(indeg[i] + 1));  // +1 self loop
}

// ---------- exclusive scan of indeg -> row_ptr (3 kernels, n<=65536) ----------
__global__ void k_scan1(const int* __restrict__ indeg, int* __restrict__ row_ptr,
                        int* __restrict__ bsum, int n) {
    __shared__ int tmp[256];
    int i = blockIdx.x * 256 + threadIdx.x;
    int v = (i < n) ? indeg[i] : 0;
    tmp[threadIdx.x] = v;
    __syncthreads();
    for (int off = 1; off < 256; off <<= 1) {
        int t = (threadIdx.x >= off) ? tmp[threadIdx.x - off] : 0;
        __syncthreads();
        tmp[threadIdx.x] += t;
        __syncthreads();
    }
    if (i < n) row_ptr[i] = tmp[threadIdx.x] - v;      // block-local exclusive
    if (threadIdx.x == 255) bsum[blockIdx.x] = tmp[255];
}

__global__ void k_scan2(int* __restrict__ bsum, int nb) {  // one block, nb<=256
    __shared__ int tmp[256];
    int v = (threadIdx.x < nb) ? bsum[threadIdx.x] : 0;
    tmp[threadIdx.x] = v;
    __syncthreads();
    for (int off = 1; off < 256; off <<= 1) {
        int t = (threadIdx.x >= off) ? tmp[threadIdx.x - off] : 0;
        __syncthreads();
        tmp[threadIdx.x] += t;
        __syncthreads();
    }
    if (threadIdx.x < nb) bsum[threadIdx.x] = tmp[threadIdx.x] - v;  // exclusive
}

__global__ void k_scan3(int* __restrict__ row_ptr, const int* __restrict__ bsum,
                        int* __restrict__ cursor, int n, int E) {
    int i = blockIdx.x * 256 + threadIdx.x;
    if (i < n) {
        int r = row_ptr[i] + bsum[blockIdx.x];
        row_ptr[i] = r;
        cursor[i] = r;
    }
    if (blockIdx.x == 0 && threadIdx.x == 0) row_ptr[n] = E;
}

// ---------- CSR fill (int atomics on cursors only) ----------
__global__ void k_fill(const int* __restrict__ src, const int* __restrict__ dst,
                       const float* __restrict__ dinv, int* __restrict__ cursor,
                       int* __restrict__ csr_src, float* __restrict__ csr_norm, int E) {
    int e = blockIdx.x * 256 + threadIdx.x;
    if (e >= E) return;
    int s = src[e], d = dst[e];
    int pos = atomicAdd(&cursor[d], 1);
    csr_src[pos] = s;
    csr_norm[pos] = dinv[s] * dinv[d];
}

// ---------- fused aggregate + bias + relu ----------
// 2 nodes per 256-thread block; 128 threads (2 waves) per node, 1 channel/thread.
__global__ __launch_bounds__(256) void k_agg_csr(
    const float* __restrict__ h, const int* __restrict__ row_ptr,
    const int* __restrict__ csr_src, const float* __restrict__ csr_norm,
    const float* __restrict__ dinv, const float* __restrict__ bias,
    float* __restrict__ o, int n)
{
    int node = blockIdx.x * 2 + (threadIdx.x >> 7);
    int c = threadIdx.x & 127;
    if (node >= n) return;
    float dv = dinv[node];
    float acc = dv * dv * h[(size_t)node * D128 + c];
    int j = row_ptr[node], end = row_ptr[node + 1];
    for (; j + 1 < end; j += 2) {
        int   s0 = csr_src[j],     s1 = csr_src[j + 1];
        float n0 = csr_norm[j],    n1 = csr_norm[j + 1];
        float h0 = h[(size_t)s0 * D128 + c];
        float h1 = h[(size_t)s1 * D128 + c];
        acc += n0 * h0 + n1 * h1;
    }
    if (j < end) acc += csr_norm[j] * h[(size_t)csr_src[j] * D128 + c];
    o[(size_t)node * D128 + c] = fmaxf(acc + bias[c], 0.f);
}

// ---------- dense GEMM: C[16 rows x 128] = A@W (K=128) ----------
__global__ __launch_bounds__(256) void k_gemm128(
    const float* __restrict__ A, const float* __restrict__ W,
    const float* __restrict__ bias, float* __restrict__ C, int accumulate)
{
    __shared__ float Ws[128 * 128];
    __shared__ float As[16 * 128];
    int tid = threadIdx.x;

    const float4* W4 = (const float4*)W;
    float4* Ws4 = (float4*)Ws;
#pragma unroll
    for (int it = 0; it < 16; ++it)
        Ws4[it * 256 + tid] = W4[it * 256 + tid];

    long long row0 = (long long)blockIdx.x * 16;
    const float4* A4 = (const float4*)(A + row0 * D128);
    float4* As4 = (float4*)As;
    As4[tid] = A4[tid];
    As4[256 + tid] = A4[256 + tid];
    __syncthreads();

    int cp = tid & 63;
    int rq = tid >> 6;
    float2 acc[4] = {{0.f,0.f},{0.f,0.f},{0.f,0.f},{0.f,0.f}};

#pragma unroll 8
    for (int k = 0; k < 128; ++k) {
        float2 w = *(const float2*)&Ws[k * 128 + cp * 2];
#pragma unroll
        for (int r = 0; r < 4; ++r) {
            float a = As[(rq * 4 + r) * 128 + k];
            acc[r].x += a * w.x;
            acc[r].y += a * w.y;
        }
    }

    float2 bv = {0.f, 0.f};
    if (bias) bv = *(const float2*)&bias[cp * 2];
#pragma unroll
    for (int r = 0; r < 4; ++r) {
        long long row = row0 + rq * 4 + r;
        float2* Cp = (float2*)&C[row * D128 + cp * 2];
        float2 v = acc[r];
        v.x += bv.x; v.y += bv.y;
        if (accumulate) { float2 old = *Cp; v.x += old.x; v.y += old.y; }
        *Cp = v;
    }
}

extern "C" void kernel_launch(void* const* d_in, const int* in_sizes, int n_in,
                              void* d_out, int out_size, void* d_ws, size_t ws_size,
                              hipStream_t stream) {
    const float* x    = (const float*)d_in[0];
    const int*   ei   = (const int*)d_in[1];
    const float* W1   = (const float*)d_in[2];
    const float* b1   = (const float*)d_in[3];
    const float* W2   = (const float*)d_in[4];
    const float* b2   = (const float*)d_in[5];
    const float* linW = (const float*)d_in[6];
    const float* linb = (const float*)d_in[7];

    int n = in_sizes[0] / D128;
    int E = in_sizes[1] / 2;
    const int* src = ei;
    const int* dst = ei + E;

    float* out = (float*)d_out;
    float* ws  = (float*)d_ws;

    // ws layout (4B words):
    // indeg[n] | dinv[n] | row_ptr[n+1] | bsum[256] | cursor[n] |
    // csr_src[E] | csr_norm[E] | x1[n*128] | x2[n*128]
    int*   indeg   = (int*)ws;
    float* dinv    = ws + n;
    int*   row_ptr = (int*)(ws + 2 * (size_t)n);
    int*   bsum    = row_ptr + (n + 1);
    int*   cursor  = bsum + 256;
    int*   csr_src = cursor + n;
    float* csr_norm= (float*)(csr_src + E);
    float* x1      = csr_norm + E;
    float* x2      = x1 + (size_t)n * D128;
    float* h       = out;  // reuse output buffer as GEMM scratch

    int gn = (n + 255) / 256;
    int gE = (E + 255) / 256;
    int gemmBlocks = n / 16;            // n % 16 == 0
    int aggBlocks  = (n + 1) / 2;       // 2 nodes per block

    // degree + dinv
    k_zero_int<<<gn, 256, 0, stream>>>(indeg, n);
    k_count<<<gE, 256, 0, stream>>>(dst, indeg, E);
    k_dinv<<<gn, 256, 0, stream>>>(indeg, dinv, n);

    // CSR build
    k_scan1<<<gn, 256, 0, stream>>>(indeg, row_ptr, bsum, n);
    k_scan2<<<1, 256, 0, stream>>>(bsum, gn);
    k_scan3<<<gn, 256, 0, stream>>>(row_ptr, bsum, cursor, n, E);
    k_fill<<<gE, 256, 0, stream>>>(src, dst, dinv, cursor, csr_src, csr_norm, E);

    // layer 1
    k_gemm128<<<gemmBlocks, 256, 0, stream>>>(x, W1, nullptr, h, 0);
    k_agg_csr<<<aggBlocks, 256, 0, stream>>>(h, row_ptr, csr_src, csr_norm, dinv, b1, x1, n);

    // layer 2
    k_gemm128<<<gemmBlocks, 256, 0, stream>>>(x1, W2, nullptr, h, 0);
    k_agg_csr<<<aggBlocks, 256, 0, stream>>>(h, row_ptr, csr_src, csr_norm, dinv, b2, x2, n);

    // final: out = x1 @ linW[0:128] + x2 @ linW[128:256] + linb
    k_gemm128<<<gemmBlocks, 256, 0, stream>>>(x1, linW, nullptr, out, 0);
    k_gemm128<<<gemmBlocks, 256, 0, stream>>>(x2, linW + 128 * 128, linb, out, 1);
}

// Round 3
// 344.526 us; speedup vs baseline: 8.3556x; 1.3100x over previous
//
#include <hip/hip_runtime.h>

// GCN: x1 = relu(Agg(x@W1)+b1); x2 = relu(Agg(x1@W2)+b2); out = [x1,x2]@linW + linb
// Agg(h)[i] = dinv[i]^2*h[i] + sum_{e: dst=i} dinv[src]*dinv[i]*h[src]
// CSR by dst (counting sort), per-node wave reduction. n=50000, D=128, E=800000.

#define D128 128

// ---------- degree / normalization ----------
__global__ void k_zero_int(int* __restrict__ p, int n) {
    int i = blockIdx.x * 256 + threadIdx.x;
    if (i < n) p[i] = 0;
}

__global__ void k_count(const int* __restrict__ dst, int* __restrict__ indeg, int E) {
    int e = blockIdx.x * 256 + threadIdx.x;
    if (e < E) atomicAdd(&indeg[dst[e]], 1);
}

__global__ void k_dinv(const int* __restrict__ indeg, float* __restrict__ dinv, int n) {
    int i = blockIdx.x * 256 + threadIdx.x;
    if (i < n) dinv[i] = rsqrtf((float)(indeg[i] + 1));  // +1 self loop
}

// ---------- exclusive scan of indeg -> row_ptr ----------
__global__ void k_scan1(const int* __restrict__ indeg, int* __restrict__ row_ptr,
                        int* __restrict__ bsum, int n) {
    __shared__ int tmp[256];
    int i = blockIdx.x * 256 + threadIdx.x;
    int v = (i < n) ? indeg[i] : 0;
    tmp[threadIdx.x] = v;
    __syncthreads();
    for (int off = 1; off < 256; off <<= 1) {
        int t = (threadIdx.x >= off) ? tmp[threadIdx.x - off] : 0;
        __syncthreads();
        tmp[threadIdx.x] += t;
        __syncthreads();
    }
    if (i < n) row_ptr[i] = tmp[threadIdx.x] - v;
    if (threadIdx.x == 255) bsum[blockIdx.x] = tmp[255];
}

__global__ void k_scan2(int* __restrict__ bsum, int nb) {  // one block, nb<=256
    __shared__ int tmp[256];
    int v = (threadIdx.x < nb) ? bsum[threadIdx.x] : 0;
    tmp[threadIdx.x] = v;
    __syncthreads();
    for (int off = 1; off < 256; off <<= 1) {
        int t = (threadIdx.x >= off) ? tmp[threadIdx.x - off] : 0;
        __syncthreads();
        tmp[threadIdx.x] += t;
        __syncthreads();
    }
    if (threadIdx.x < nb) bsum[threadIdx.x] = tmp[threadIdx.x] - v;
}

__global__ void k_scan3(int* __restrict__ row_ptr, const int* __restrict__ bsum,
                        int* __restrict__ cursor, int n, int E) {
    int i = blockIdx.x * 256 + threadIdx.x;
    if (i < n) {
        int r = row_ptr[i] + bsum[blockIdx.x];
        row_ptr[i] = r;
        cursor[i] = r;
    }
    if (blockIdx.x == 0 && threadIdx.x == 0) row_ptr[n] = E;
}

// ---------- CSR fill (int atomics on cursors only) ----------
__global__ void k_fill(const int* __restrict__ src, const int* __restrict__ dst,
                       const float* __restrict__ dinv, int* __restrict__ cursor,
                       int* __restrict__ csr_src, float* __restrict__ csr_norm, int E) {
    int e = blockIdx.x * 256 + threadIdx.x;
    if (e >= E) return;
    int s = src[e], d = dst[e];
    int pos = atomicAdd(&cursor[d], 1);
    csr_src[pos] = s;
    csr_norm[pos] = dinv[s] * dinv[d];
}

// ---------- fused aggregate + bias + relu ----------
// 1 wave per node, float2 per lane (128 channels / 64 lanes), 4 nodes / block.
__global__ __launch_bounds__(256) void k_agg_csr(
    const float* __restrict__ h, const int* __restrict__ row_ptr,
    const int* __restrict__ csr_src, const float* __restrict__ csr_norm,
    const float* __restrict__ dinv, const float* __restrict__ bias,
    float* __restrict__ o, int n)
{
    int node = blockIdx.x * 4 + (threadIdx.x >> 6);
    int lane = threadIdx.x & 63;
    if (node >= n) return;
    const float2* h2 = (const float2*)h;
    float dv = dinv[node];
    float s2 = dv * dv;
    float2 hv = h2[(size_t)node * 64 + lane];
    float ax = s2 * hv.x, ay = s2 * hv.y;
    int j = row_ptr[node], end = row_ptr[node + 1];
    for (; j + 3 < end; j += 4) {
        int   s0 = csr_src[j],   s1 = csr_src[j+1],  s2i = csr_src[j+2], s3 = csr_src[j+3];
        float n0 = csr_norm[j],  n1 = csr_norm[j+1], n2 = csr_norm[j+2], n3 = csr_norm[j+3];
        float2 v0 = h2[(size_t)s0  * 64 + lane];
        float2 v1 = h2[(size_t)s1  * 64 + lane];
        float2 v2 = h2[(size_t)s2i * 64 + lane];
        float2 v3 = h2[(size_t)s3  * 64 + lane];
        ax += n0 * v0.x + n1 * v1.x + n2 * v2.x + n3 * v3.x;
        ay += n0 * v0.y + n1 * v1.y + n2 * v2.y + n3 * v3.y;
    }
    for (; j < end; ++j) {
        int s = csr_src[j];
        float nm = csr_norm[j];
        float2 v = h2[(size_t)s * 64 + lane];
        ax += nm * v.x;
        ay += nm * v.y;
    }
    float2 bv = ((const float2*)bias)[lane];
    float2 ov = {fmaxf(ax + bv.x, 0.f), fmaxf(ay + bv.y, 0.f)};
    ((float2*)o)[(size_t)node * 64 + lane] = ov;
}

// ---------- dense GEMM: C[32 rows x 128] = A@W (K=128), 4x4 per thread ----------
__global__ __launch_bounds__(256) void k_gemm128(
    const float* __restrict__ A, const float* __restrict__ W,
    const float* __restrict__ bias, float* __restrict__ C, int accumulate, int n)
{
    __shared__ float Ws[128 * 128];   // 64 KB
    __shared__ float As[32 * 128];    // 16 KB
    int tid = threadIdx.x;

    const float4* W4 = (const float4*)W;
    float4* Ws4 = (float4*)Ws;
#pragma unroll
    for (int it = 0; it < 16; ++it)
        Ws4[it * 256 + tid] = W4[it * 256 + tid];

    long long row0 = (long long)blockIdx.x * 32;
    const float4* A4 = (const float4*)(A + row0 * D128);
    float4* As4 = (float4*)As;
#pragma unroll
    for (int it = 0; it < 4; ++it) {
        int f = it * 256 + tid;           // float4 index within 32x128 tile
        int r = f >> 5;                   // row within tile
        float4 v = {0.f, 0.f, 0.f, 0.f};
        if (row0 + r < n) v = A4[f];
        As4[f] = v;
    }
    __syncthreads();

    int cg = tid & 31;   // col group: cols cg*4 .. cg*4+3
    int rg = tid >> 5;   // row group: rows rg*4 .. rg*4+3
    float4 acc[4];
#pragma unroll
    for (int r = 0; r < 4; ++r) acc[r] = {0.f, 0.f, 0.f, 0.f};

#pragma unroll 8
    for (int k = 0; k < 128; ++k) {
        float4 w = Ws4[k * 32 + cg];
#pragma unroll
        for (int r = 0; r < 4; ++r) {
            float a = As[(rg * 4 + r) * 128 + k];  // half-wave broadcast
            acc[r].x += a * w.x;
            acc[r].y += a * w.y;
            acc[r].z += a * w.z;
            acc[r].w += a * w.w;
        }
    }

    float4 bv = {0.f, 0.f, 0.f, 0.f};
    if (bias) bv = ((const float4*)bias)[cg];
#pragma unroll
    for (int r = 0; r < 4; ++r) {
        long long row = row0 + rg * 4 + r;
        if (row >= n) break;
        float4* Cp = (float4*)&C[row * D128 + cg * 4];
        float4 v = acc[r];
        v.x += bv.x; v.y += bv.y; v.z += bv.z; v.w += bv.w;
        if (accumulate) {
            float4 old = *Cp;
            v.x += old.x; v.y += old.y; v.z += old.z; v.w += old.w;
        }
        *Cp = v;
    }
}

extern "C" void kernel_launch(void* const* d_in, const int* in_sizes, int n_in,
                              void* d_out, int out_size, void* d_ws, size_t ws_size,
                              hipStream_t stream) {
    const float* x    = (const float*)d_in[0];
    const int*   ei   = (const int*)d_in[1];
    const float* W1   = (const float*)d_in[2];
    const float* b1   = (const float*)d_in[3];
    const float* W2   = (const float*)d_in[4];
    const float* b2   = (const float*)d_in[5];
    const float* linW = (const float*)d_in[6];
    const float* linb = (const float*)d_in[7];

    int n = in_sizes[0] / D128;
    int E = in_sizes[1] / 2;
    const int* src = ei;
    const int* dst = ei + E;

    float* out = (float*)d_out;
    float* ws  = (float*)d_ws;

    // ws layout (4B words):
    // indeg[n] | dinv[n] | row_ptr[n+1] | bsum[256] | cursor[n] |
    // csr_src[E] | csr_norm[E] | x1[n*128] | x2[n*128]
    int*   indeg   = (int*)ws;
    float* dinv    = ws + n;
    int*   row_ptr = (int*)(ws + 2 * (size_t)n);
    int*   bsum    = row_ptr + (n + 1);
    int*   cursor  = bsum + 256;
    int*   csr_src = cursor + n;
    float* csr_norm= (float*)(csr_src + E);
    float* x1      = csr_norm + E;
    float* x2      = x1 + (size_t)n * D128;
    float* h       = out;  // reuse output buffer as GEMM scratch

    int gn = (n + 255) / 256;
    int gE = (E + 255) / 256;
    int gemmBlocks = (n + 31) / 32;
    int aggBlocks  = (n + 3) / 4;

    // degree + dinv
    k_zero_int<<<gn, 256, 0, stream>>>(indeg, n);
    k_count<<<gE, 256, 0, stream>>>(dst, indeg, E);
    k_dinv<<<gn, 256, 0, stream>>>(indeg, dinv, n);

    // CSR build
    k_scan1<<<gn, 256, 0, stream>>>(indeg, row_ptr, bsum, n);
    k_scan2<<<1, 256, 0, stream>>>(bsum, gn);
    k_scan3<<<gn, 256, 0, stream>>>(row_ptr, bsum, cursor, n, E);
    k_fill<<<gE, 256, 0, stream>>>(src, dst, dinv, cursor, csr_src, csr_norm, E);

    // layer 1
    k_gemm128<<<gemmBlocks, 256, 0, stream>>>(x, W1, nullptr, h, 0, n);
    k_agg_csr<<<aggBlocks, 256, 0, stream>>>(h, row_ptr, csr_src, csr_norm, dinv, b1, x1, n);

    // layer 2
    k_gemm128<<<gemmBlocks, 256, 0, stream>>>(x1, W2, nullptr, h, 0, n);
    k_agg_csr<<<aggBlocks, 256, 0, stream>>>(h, row_ptr, csr_src, csr_norm, dinv, b2, x2, n);

    // final: out = x1 @ linW[0:128] + x2 @ linW[128:256] + linb
    k_gemm128<<<gemmBlocks, 256, 0, stream>>>(x1, linW, nullptr, out, 0, n);
    k_gemm128<<<gemmBlocks, 256, 0, stream>>>(x2, linW + 128 * 128, linb, out, 1, n);
}